// Round 4
// baseline (931.717 us; speedup 1.0000x reference)
//
#include <hip/hip_runtime.h>
#include <math.h>

#define H 2048
#define V 50257
#define S 2048
#define G 768            // persistent grid: 3 blocks/CU on 256 CUs -> co-resident
#define NTHR 256

__device__ inline float dot4(float4 a, float4 b) {
  return a.x * b.x + a.y * b.y + a.z * b.z + a.w * b.w;
}

__device__ inline float wave_sum(float v) {
#pragma unroll
  for (int o = 32; o > 0; o >>= 1) v += __shfl_down(v, o, 64);
  return v;
}

__device__ inline float wave_max(float v) {
#pragma unroll
  for (int o = 32; o > 0; o >>= 1) v = fmaxf(v, __shfl_down(v, o, 64));
  return v;
}

// Increasing-target grid barrier. cnt starts at 0 (init kernel each call).
// Barrier b: each block adds 1, waits until cnt >= b*G. Monotone-safe.
__device__ inline void grid_barrier(unsigned* cnt, unsigned target) {
  __syncthreads();
  if (threadIdx.x == 0) {
    __threadfence();  // release: make prior writes device-visible
    __hip_atomic_fetch_add(cnt, 1u, __ATOMIC_RELEASE, __HIP_MEMORY_SCOPE_AGENT);
    while (__hip_atomic_load(cnt, __ATOMIC_RELAXED, __HIP_MEMORY_SCOPE_AGENT) < target) {
      __builtin_amdgcn_s_sleep(1);
    }
    __threadfence();  // acquire: invalidate stale cached lines
  }
  __syncthreads();
}

__global__ void init_sem_kernel(unsigned* cnt) {
  if (threadIdx.x == 0) *cnt = 0;
}

__global__ __launch_bounds__(NTHR, 3) void mega_kernel(
    const int* __restrict__ word, const float* __restrict__ lasth,
    const float* __restrict__ enc, const float* __restrict__ emb,
    const float* __restrict__ w_ih0, const float* __restrict__ w_hh0,
    const float* __restrict__ b_ih0, const float* __restrict__ b_hh0,
    const float* __restrict__ w_ih1, const float* __restrict__ w_hh1,
    const float* __restrict__ b_ih1, const float* __restrict__ b_hh1,
    const float* __restrict__ wa, const float* __restrict__ w_out,
    const float* __restrict__ b_out,
    float* __restrict__ out,        // d_out: [logits | h0 | h1 | attn]
    float* __restrict__ part,       // ws 32*H
    float* __restrict__ v,          // ws H
    float* __restrict__ e,          // ws S
    float* __restrict__ u,          // ws 2H: [h1 | context]
    float* __restrict__ h0,         // ws H
    float* __restrict__ pairs,      // ws 2*G
    unsigned* __restrict__ cnt) {
  const int t = threadIdx.x;
  const int b = blockIdx.x;
  const int lane = t & 63, wid = t >> 6;
  float* h0_out   = out + V;
  float* h1_out   = out + V + H;
  float* attn_out = out + V + 2 * H;

  __shared__ float red[6][4];
  __shared__ float s4[4];
  __shared__ float wtile[64];
  __shared__ float lm[4], ls[4];
  __shared__ float bc;
  unsigned bar = 0;

  // ---- P0 / P1: GRU layers (row-parallel, ~3 outputs per block) ----
#pragma unroll 1
  for (int layer = 0; layer < 2; layer++) {
    const float* w_ih = layer ? w_ih1 : w_ih0;
    const float* w_hh = layer ? w_hh1 : w_hh0;
    const float* b_ih = layer ? b_ih1 : b_ih0;
    const float* b_hh = layer ? b_hh1 : b_hh0;
    const float* x    = layer ? h0 : (emb + (size_t)word[0] * H);
    const float* hprev = lasth + layer * H;
    float* hws = layer ? u : h0;            // u[0:H] holds h1
    float* hd  = layer ? h1_out : h0_out;
    const float4* x4 = (const float4*)x;
    const float4* h4 = (const float4*)hprev;
    float4 xa = x4[t], xb = x4[t + 256];
    float4 ha = h4[t], hb = h4[t + 256];
    for (int i = b; i < H; i += G) {
      float acc[6];
#pragma unroll
      for (int g = 0; g < 3; g++) {
        const float4* wi = (const float4*)(w_ih + (size_t)(g * H + i) * H);
        const float4* wh = (const float4*)(w_hh + (size_t)(g * H + i) * H);
        acc[g]     = dot4(wi[t], xa) + dot4(wi[t + 256], xb);
        acc[3 + g] = dot4(wh[t], ha) + dot4(wh[t + 256], hb);
      }
#pragma unroll
      for (int d = 0; d < 6; d++) {
        float s_ = wave_sum(acc[d]);
        if (lane == 0) red[d][wid] = s_;
      }
      __syncthreads();
      if (t == 0) {
        float gi_r = red[0][0] + red[0][1] + red[0][2] + red[0][3] + b_ih[i];
        float gi_z = red[1][0] + red[1][1] + red[1][2] + red[1][3] + b_ih[H + i];
        float gi_n = red[2][0] + red[2][1] + red[2][2] + red[2][3] + b_ih[2 * H + i];
        float gh_r = red[3][0] + red[3][1] + red[3][2] + red[3][3] + b_hh[i];
        float gh_z = red[4][0] + red[4][1] + red[4][2] + red[4][3] + b_hh[H + i];
        float gh_n = red[5][0] + red[5][1] + red[5][2] + red[5][3] + b_hh[2 * H + i];
        float r = 1.f / (1.f + expf(-(gi_r + gh_r)));
        float z = 1.f / (1.f + expf(-(gi_z + gh_z)));
        float n = tanhf(gi_n + r * gh_n);
        float h = (1.f - z) * n + z * hprev[i];
        hws[i] = h;
        hd[i] = h;
      }
      __syncthreads();
    }
    grid_barrier(cnt, (++bar) * G);   // BAR1 after gru0, BAR2 after gru1
  }

  // ---- P2: v partials: part[jt][k] = sum_{64 rows} h1[j]*wa[j][k] ----
  if (b < 256) {
    const int kb = b & 7, jt = b >> 3;
    const int k = kb * 256 + t, j0 = jt * 64;
    float acc = 0.f;
#pragma unroll 4
    for (int j = 0; j < 64; j++)
      acc += u[j0 + j] * wa[(size_t)(j0 + j) * H + k];
    part[(size_t)jt * H + k] = acc;
  }
  grid_barrier(cnt, (++bar) * G);     // BAR3

  // ---- P3: combine v ----
  if (b < 8) {
    const int k = b * 256 + t;
    float acc = 0.f;
#pragma unroll
    for (int jt = 0; jt < 32; jt++) acc += part[(size_t)jt * H + k];
    v[k] = acc;
  }
  grid_barrier(cnt, (++bar) * G);     // BAR4

  // ---- P4: energies e[row] = dot(enc[row], v), wave per row ----
  {
    const int wg = b * 4 + wid;
    if (wg < S) {
      const float4* r4 = (const float4*)(enc + (size_t)wg * H);
      const float4* v4 = (const float4*)v;
      float acc = 0.f;
#pragma unroll
      for (int k = 0; k < 8; k++) {
        int idx = lane + 64 * k;
        acc += dot4(r4[idx], v4[idx]);
      }
      acc = wave_sum(acc);
      if (lane == 0) e[wg] = acc;
    }
  }
  grid_barrier(cnt, (++bar) * G);     // BAR5

  // ---- P5: per-block redundant softmax stats + ctx partials + attn ----
  {
    float ev[8];
    float m = -INFINITY;
#pragma unroll
    for (int r = 0; r < 8; r++) {
      ev[r] = e[t + 256 * r];
      m = fmaxf(m, ev[r]);
    }
    float mw = wave_max(m);
    if (lane == 0) s4[wid] = mw;
    __syncthreads();
    const float M = fmaxf(fmaxf(s4[0], s4[1]), fmaxf(s4[2], s4[3]));
    float se = 0.f;
#pragma unroll
    for (int r = 0; r < 8; r++) se += expf(ev[r] - M);
    float sw = wave_sum(se);
    __syncthreads();
    if (lane == 0) s4[wid] = sw;
    __syncthreads();
    const float inv = 1.f / (s4[0] + s4[1] + s4[2] + s4[3]);
    if (b < 256) {
      const int kb = b & 7, jt = b >> 3;
      const int k = kb * 256 + t, j0 = jt * 64;
      if (t < 64) wtile[t] = expf(e[j0 + t] - M) * inv;
      __syncthreads();
      float acc = 0.f;
#pragma unroll 4
      for (int j = 0; j < 64; j++)
        acc += wtile[j] * enc[(size_t)(j0 + j) * H + k];
      part[(size_t)jt * H + k] = acc;
    }
    if (b < 8) attn_out[b * 256 + t] = expf(e[b * 256 + t] - M) * inv;
  }
  grid_barrier(cnt, (++bar) * G);     // BAR6

  // ---- P6: combine context -> u[H:2H] ----
  if (b < 8) {
    const int k = b * 256 + t;
    float acc = 0.f;
#pragma unroll
    for (int jt = 0; jt < 32; jt++) acc += part[(size_t)jt * H + k];
    u[H + k] = acc;
  }
  grid_barrier(cnt, (++bar) * G);     // BAR7

  // ---- P7: logits (wave per row) + per-block (max,sumexp) pair ----
  {
    const int wg = b * 4 + wid;
    const float4* u4 = (const float4*)u;
    float m_run = -INFINITY, s_run = 0.f;
    for (int row = wg; row < V; row += G * 4) {
      const float4* r4 = (const float4*)(w_out + (size_t)row * (2 * H));
      float acc = 0.f;
#pragma unroll
      for (int k = 0; k < 16; k++) {
        int idx = lane + 64 * k;
        acc += dot4(r4[idx], u4[idx]);
      }
      acc = wave_sum(acc);
      if (lane == 0) {
        float logit = acc + b_out[row];
        out[row] = logit;
        float Mn = fmaxf(m_run, logit);
        s_run = s_run * expf(m_run - Mn) + expf(logit - Mn);
        m_run = Mn;
      }
    }
    if (lane == 0) { lm[wid] = m_run; ls[wid] = s_run; }
    __syncthreads();
    if (t == 0) {
      float Mg = -INFINITY, Sg = 0.f;
#pragma unroll
      for (int i = 0; i < 4; i++) {
        float Mn = fmaxf(Mg, lm[i]);
        Sg = Sg * expf(Mg - Mn) + ls[i] * expf(lm[i] - Mn);
        Mg = Mn;
      }
      pairs[2 * b] = Mg;
      pairs[2 * b + 1] = Sg;
    }
  }
  grid_barrier(cnt, (++bar) * G);     // BAR8

  // ---- P8: per-block redundant LSE combine + in-place subtract ----
  {
    float m = -INFINITY, se = 0.f;
    for (int i = t; i < G; i += 256) {
      float mb = pairs[2 * i], sb = pairs[2 * i + 1];
      float Mn = fmaxf(m, mb);
      se = se * expf(m - Mn) + sb * expf(mb - Mn);
      m = Mn;
    }
#pragma unroll
    for (int o = 32; o > 0; o >>= 1) {
      float mo = __shfl_down(m, o, 64);
      float so = __shfl_down(se, o, 64);
      float Mn = fmaxf(m, mo);
      se = se * expf(m - Mn) + so * expf(mo - Mn);
      m = Mn;
    }
    __syncthreads();   // protect lm/ls reuse
    if (lane == 0) { lm[wid] = m; ls[wid] = se; }
    __syncthreads();
    if (t == 0) {
      float Mg = -INFINITY, Sg = 0.f;
#pragma unroll
      for (int i = 0; i < 4; i++) {
        float Mn = fmaxf(Mg, lm[i]);
        Sg = Sg * expf(Mg - Mn) + ls[i] * expf(lm[i] - Mn);
        Mg = Mn;
      }
      bc = Mg + logf(Sg);
    }
    __syncthreads();
    const float c = bc;
    for (int i = b * 256 + t; i < V; i += G * 256) out[i] -= c;
  }
}

extern "C" void kernel_launch(void* const* d_in, const int* in_sizes, int n_in,
                              void* d_out, int out_size, void* d_ws, size_t ws_size,
                              hipStream_t stream) {
  const int*   word  = (const int*)d_in[0];
  const float* lasth = (const float*)d_in[1];
  const float* enc   = (const float*)d_in[2];
  const float* emb   = (const float*)d_in[3];
  const float* w_ih0 = (const float*)d_in[4];
  const float* w_hh0 = (const float*)d_in[5];
  const float* b_ih0 = (const float*)d_in[6];
  const float* b_hh0 = (const float*)d_in[7];
  const float* w_ih1 = (const float*)d_in[8];
  const float* w_hh1 = (const float*)d_in[9];
  const float* b_ih1 = (const float*)d_in[10];
  const float* b_hh1 = (const float*)d_in[11];
  const float* wa    = (const float*)d_in[12];
  // d_in[13] = ba: constant across s -> cancels in softmax.
  const float* w_out = (const float*)d_in[14];
  const float* b_out = (const float*)d_in[15];

  float* out = (float*)d_out;

  float* wsf   = (float*)d_ws;
  float* part  = wsf;                 // 32*H = 65536
  float* v     = wsf + 65536;         // H
  float* e     = wsf + 67584;         // S
  float* u     = wsf + 69632;         // 2H
  float* h0    = wsf + 73728;         // H
  float* pairs = wsf + 75776;         // 2*G = 1536
  unsigned* cnt = (unsigned*)(wsf + 77312);

  init_sem_kernel<<<1, 64, 0, stream>>>(cnt);
  mega_kernel<<<G, NTHR, 0, stream>>>(word, lasth, enc, emb,
                                      w_ih0, w_hh0, b_ih0, b_hh0,
                                      w_ih1, w_hh1, b_ih1, b_hh1,
                                      wa, w_out, b_out, out,
                                      part, v, e, u, h0, pairs, cnt);
}

// Round 5
// 202.345 us; speedup vs baseline: 4.6046x; 4.6046x over previous
//
#include <hip/hip_runtime.h>
#include <math.h>

#define H 2048
#define V 50257
#define S 2048

typedef float f32x4 __attribute__((ext_vector_type(4)));

__device__ inline float4 ntload4(const float* p) {
  f32x4 v = __builtin_nontemporal_load((const f32x4*)p);
  float4 r; r.x = v.x; r.y = v.y; r.z = v.z; r.w = v.w;
  return r;
}

__device__ inline float dot4(float4 a, float4 b) {
  return a.x * b.x + a.y * b.y + a.z * b.z + a.w * b.w;
}

__device__ inline float wave_sum(float v) {
#pragma unroll
  for (int o = 32; o > 0; o >>= 1) v += __shfl_down(v, o, 64);
  return v;
}

__device__ inline float wave_max(float v) {
#pragma unroll
  for (int o = 32; o > 0; o >>= 1) v = fmaxf(v, __shfl_down(v, o, 64));
  return v;
}

// One block (256 threads) per output unit i: 6 dot products of length H.
__global__ __launch_bounds__(256) void gru_kernel(
    const float* __restrict__ w_ih, const float* __restrict__ w_hh,
    const float* __restrict__ b_ih, const float* __restrict__ b_hh,
    const float* __restrict__ x_base, const int* __restrict__ word,
    const float* __restrict__ hprev,
    float* __restrict__ hout_ws, float* __restrict__ hout_d) {
  const float* x = word ? (x_base + (size_t)word[0] * H) : x_base;
  const int i = blockIdx.x;
  const int t = threadIdx.x;
  const float4* x4 = (const float4*)x;
  const float4* h4 = (const float4*)hprev;
  float acc[6];
#pragma unroll
  for (int d = 0; d < 6; d++) acc[d] = 0.f;
#pragma unroll
  for (int g = 0; g < 3; g++) {
    const float* wi = w_ih + (size_t)(g * H + i) * H;
    const float* wh = w_hh + (size_t)(g * H + i) * H;
    float4 xa = x4[t], xb = x4[t + 256];
    float4 ha = h4[t], hb = h4[t + 256];
    acc[g]     = dot4(ntload4(wi + 4 * t), xa) +
                 dot4(ntload4(wi + 4 * (t + 256)), xb);
    acc[3 + g] = dot4(ntload4(wh + 4 * t), ha) +
                 dot4(ntload4(wh + 4 * (t + 256)), hb);
  }
  __shared__ float red[6][4];
  const int lane = t & 63, wid = t >> 6;
#pragma unroll
  for (int d = 0; d < 6; d++) {
    float s_ = wave_sum(acc[d]);
    if (lane == 0) red[d][wid] = s_;
  }
  __syncthreads();
  if (t == 0) {
    float gi_r = red[0][0] + red[0][1] + red[0][2] + red[0][3] + b_ih[i];
    float gi_z = red[1][0] + red[1][1] + red[1][2] + red[1][3] + b_ih[H + i];
    float gi_n = red[2][0] + red[2][1] + red[2][2] + red[2][3] + b_ih[2 * H + i];
    float gh_r = red[3][0] + red[3][1] + red[3][2] + red[3][3] + b_hh[i];
    float gh_z = red[4][0] + red[4][1] + red[4][2] + red[4][3] + b_hh[H + i];
    float gh_n = red[5][0] + red[5][1] + red[5][2] + red[5][3] + b_hh[2 * H + i];
    float r = 1.f / (1.f + expf(-(gi_r + gh_r)));
    float z = 1.f / (1.f + expf(-(gi_z + gh_z)));
    float n = tanhf(gi_n + r * gh_n);
    float h = (1.f - z) * n + z * hprev[i];
    hout_ws[i] = h;
    hout_d[i] = h;
  }
}

// part[jt][k] = sum_{j in tile jt} coef[j] * mat[j][k].  grid=(8, 32).
__global__ __launch_bounds__(256) void colsum_part_kernel(
    const float* __restrict__ mat, const float* __restrict__ coef,
    float* __restrict__ part) {
  const int k = blockIdx.x * 256 + threadIdx.x;
  const int jt = blockIdx.y;
  const int j0 = jt * 64;
  float acc = 0.f;
#pragma unroll 4
  for (int j = j0; j < j0 + 64; j++)
    acc += coef[j] * __builtin_nontemporal_load(&mat[(size_t)j * H + k]);
  part[(size_t)jt * H + k] = acc;
}

// out[k] = sum over 32 partial tiles.
__global__ __launch_bounds__(256) void combine_kernel(
    const float* __restrict__ part, float* __restrict__ out) {
  const int k = blockIdx.x * 256 + threadIdx.x;
  float acc = 0.f;
#pragma unroll
  for (int jt = 0; jt < 32; jt++) acc += part[(size_t)jt * H + k];
  out[k] = acc;
}

// e[row] = dot(enc[row], v).  One wave per row, 4 rows per block.
__global__ __launch_bounds__(256) void energies_kernel(
    const float* __restrict__ enc, const float* __restrict__ v,
    float* __restrict__ e) {
  const int wid = threadIdx.x >> 6, lane = threadIdx.x & 63;
  const int row = blockIdx.x * 4 + wid;
  const float4* r4 = (const float4*)(enc + (size_t)row * H);
  const float4* v4 = (const float4*)v;
  float acc = 0.f;
#pragma unroll
  for (int k = 0; k < 8; k++) {
    int idx = lane + 64 * k;
    acc += dot4(r4[idx], v4[idx]);
  }
  acc = wave_sum(acc);
  if (lane == 0) e[row] = acc;
}

// Redundant per-block softmax stats over e, then partial context colsum.
__global__ __launch_bounds__(256) void softmax_ctx_part_kernel(
    const float* __restrict__ enc, const float* __restrict__ e,
    float* __restrict__ part, float* __restrict__ attn_out) {
  const int t = threadIdx.x;
  const int kb = blockIdx.x;   // 0..7
  const int jt = blockIdx.y;   // 0..31
  const int lane = t & 63, wid = t >> 6;
  __shared__ float sred[4];
  __shared__ float wtile[64];
  float ev[8];
  float m = -INFINITY;
#pragma unroll
  for (int r = 0; r < 8; r++) {
    ev[r] = e[t + 256 * r];
    m = fmaxf(m, ev[r]);
  }
  float mw = wave_max(m);
  if (lane == 0) sred[wid] = mw;
  __syncthreads();
  const float M = fmaxf(fmaxf(sred[0], sred[1]), fmaxf(sred[2], sred[3]));
  float se = 0.f;
#pragma unroll
  for (int r = 0; r < 8; r++) se += expf(ev[r] - M);
  float sw = wave_sum(se);
  __syncthreads();
  if (lane == 0) sred[wid] = sw;
  __syncthreads();
  const float inv = 1.f / (sred[0] + sred[1] + sred[2] + sred[3]);
  const int j0 = jt * 64;
  if (t < 64) wtile[t] = expf(e[j0 + t] - M) * inv;
  __syncthreads();
  if (jt == 0) {
    const int s_idx = kb * 256 + t;
    attn_out[s_idx] = expf(e[s_idx] - M) * inv;
  }
  const int k = kb * 256 + t;
  float acc = 0.f;
#pragma unroll 4
  for (int j = 0; j < 64; j++)
    acc += wtile[j] * enc[(size_t)(j0 + j) * H + k];
  part[(size_t)jt * H + k] = acc;
}

// logits[row] = dot(w_out[row], u) + b_out[row]; per-block (max, sumexp).
__global__ __launch_bounds__(256) void logits_kernel(
    const float* __restrict__ w_out, const float* __restrict__ b_out,
    const float* __restrict__ u, float* __restrict__ logits,
    float* __restrict__ pairs) {
  const int wid = threadIdx.x >> 6, lane = threadIdx.x & 63;
  const int row = blockIdx.x * 4 + wid;
  __shared__ float lvals[4];
  float logit = -INFINITY;
  if (row < V) {
    const float* r = w_out + (size_t)row * (2 * H);
    const float4* u4 = (const float4*)u;
    float acc = 0.f;
#pragma unroll
    for (int k = 0; k < 16; k++) {
      int idx = lane + 64 * k;
      acc += dot4(ntload4(r + 4 * idx), u4[idx]);
    }
    acc = wave_sum(acc);
    logit = acc + b_out[row];
    if (lane == 0) logits[row] = logit;
  }
  if (lane == 0) lvals[wid] = logit;
  __syncthreads();
  if (threadIdx.x == 0) {
    float M = fmaxf(fmaxf(lvals[0], lvals[1]), fmaxf(lvals[2], lvals[3]));
    float sumexp = expf(lvals[0] - M) + expf(lvals[1] - M) +
                   expf(lvals[2] - M) + expf(lvals[3] - M);
    pairs[2 * blockIdx.x] = M;
    pairs[2 * blockIdx.x + 1] = sumexp;
  }
}

// One block: combine per-block (max,sumexp) pairs -> scalar c = logsumexp.
__global__ __launch_bounds__(1024) void lse_combine_kernel(
    const float* __restrict__ pairs, int npairs, float* __restrict__ c_out) {
  const int t = threadIdx.x;
  const int lane = t & 63, wid = t >> 6;
  __shared__ float sm[16], ss[16];
  float M = -INFINITY, Ssum = 0.f;
  for (int i = t; i < npairs; i += 1024) {
    float mb = pairs[2 * i], sb = pairs[2 * i + 1];
    float Mn = fmaxf(M, mb);
    Ssum = Ssum * expf(M - Mn) + sb * expf(mb - Mn);
    M = Mn;
  }
#pragma unroll
  for (int o = 32; o > 0; o >>= 1) {
    float mo = __shfl_down(M, o, 64);
    float so = __shfl_down(Ssum, o, 64);
    float Mn = fmaxf(M, mo);
    Ssum = Ssum * expf(M - Mn) + so * expf(mo - Mn);
    M = Mn;
  }
  if (lane == 0) { sm[wid] = M; ss[wid] = Ssum; }
  __syncthreads();
  if (t == 0) {
    float Mg = -INFINITY, Sg = 0.f;
    for (int i = 0; i < 16; i++) {
      float Mn = fmaxf(Mg, sm[i]);
      Sg = Sg * expf(Mg - Mn) + ss[i] * expf(sm[i] - Mn);
      Mg = Mn;
    }
    c_out[0] = Mg + logf(Sg);
  }
}

__global__ __launch_bounds__(256) void sub_kernel(
    float* __restrict__ out, const float* __restrict__ c) {
  const int i = blockIdx.x * 256 + threadIdx.x;
  if (i < V) out[i] -= c[0];
}

extern "C" void kernel_launch(void* const* d_in, const int* in_sizes, int n_in,
                              void* d_out, int out_size, void* d_ws, size_t ws_size,
                              hipStream_t stream) {
  const int*   word  = (const int*)d_in[0];
  const float* lasth = (const float*)d_in[1];
  const float* enc   = (const float*)d_in[2];
  const float* emb   = (const float*)d_in[3];
  const float* w_ih0 = (const float*)d_in[4];
  const float* w_hh0 = (const float*)d_in[5];
  const float* b_ih0 = (const float*)d_in[6];
  const float* b_hh0 = (const float*)d_in[7];
  const float* w_ih1 = (const float*)d_in[8];
  const float* w_hh1 = (const float*)d_in[9];
  const float* b_ih1 = (const float*)d_in[10];
  const float* b_hh1 = (const float*)d_in[11];
  const float* wa    = (const float*)d_in[12];
  // d_in[13] = ba: constant across s -> cancels in softmax.
  const float* w_out = (const float*)d_in[14];
  const float* b_out = (const float*)d_in[15];

  float* out      = (float*)d_out;
  float* h0_out   = out + V;
  float* h1_out   = out + V + H;
  float* attn_out = out + V + 2 * H;

  float* wsf   = (float*)d_ws;
  float* part  = wsf;                // 32*H
  float* v     = wsf + 65536;        // H
  float* e     = wsf + 67584;        // S
  float* u     = wsf + 69632;        // 2H
  float* h0    = wsf + 73728;        // H
  float* pairs = wsf + 75776;        // 2*12565
  float* cbuf  = wsf + 100908;       // 1

  const int nblk = (V + 3) / 4;      // 12565

  gru_kernel<<<H, 256, 0, stream>>>(w_ih0, w_hh0, b_ih0, b_hh0, emb, word,
                                    lasth, h0, h0_out);
  gru_kernel<<<H, 256, 0, stream>>>(w_ih1, w_hh1, b_ih1, b_hh1, h0, nullptr,
                                    lasth + H, u, h1_out);
  colsum_part_kernel<<<dim3(8, 32), 256, 0, stream>>>(wa, u, part);
  combine_kernel<<<8, 256, 0, stream>>>(part, v);
  energies_kernel<<<S / 4, 256, 0, stream>>>(enc, v, e);
  softmax_ctx_part_kernel<<<dim3(8, 32), 256, 0, stream>>>(enc, e, part,
                                                           attn_out);
  combine_kernel<<<8, 256, 0, stream>>>(part, u + H);
  logits_kernel<<<nblk, 256, 0, stream>>>(w_out, b_out, u, out, pairs);
  lse_combine_kernel<<<1, 1024, 0, stream>>>(pairs, nblk, cbuf);
  sub_kernel<<<(V + 255) / 256, 256, 0, stream>>>(out, cbuf);
}

// Round 6
// 200.402 us; speedup vs baseline: 4.6492x; 1.0097x over previous
//
#include <hip/hip_runtime.h>
#include <math.h>

#define H 2048
#define V 50257
#define S 2048

typedef float f32x4 __attribute__((ext_vector_type(4)));

__device__ inline float4 ntload4(const float* p) {
  f32x4 v = __builtin_nontemporal_load((const f32x4*)p);
  float4 r; r.x = v.x; r.y = v.y; r.z = v.z; r.w = v.w;
  return r;
}

__device__ inline float dot4(float4 a, float4 b) {
  return a.x * b.x + a.y * b.y + a.z * b.z + a.w * b.w;
}

__device__ inline float wave_sum(float v) {
#pragma unroll
  for (int o = 32; o > 0; o >>= 1) v += __shfl_down(v, o, 64);
  return v;
}

__device__ inline float wave_max(float v) {
#pragma unroll
  for (int o = 32; o > 0; o >>= 1) v = fmaxf(v, __shfl_down(v, o, 64));
  return v;
}

// One block (256 threads) per output unit i: 6 dot products of length H.
__global__ __launch_bounds__(256) void gru_kernel(
    const float* __restrict__ w_ih, const float* __restrict__ w_hh,
    const float* __restrict__ b_ih, const float* __restrict__ b_hh,
    const float* __restrict__ x_base, const int* __restrict__ word,
    const float* __restrict__ hprev,
    float* __restrict__ hout_ws, float* __restrict__ hout_d) {
  const float* x = word ? (x_base + (size_t)word[0] * H) : x_base;
  const int i = blockIdx.x;
  const int t = threadIdx.x;
  const float4* x4 = (const float4*)x;
  const float4* h4 = (const float4*)hprev;
  float acc[6];
#pragma unroll
  for (int d = 0; d < 6; d++) acc[d] = 0.f;
#pragma unroll
  for (int g = 0; g < 3; g++) {
    const float* wi = w_ih + (size_t)(g * H + i) * H;
    const float* wh = w_hh + (size_t)(g * H + i) * H;
    float4 xa = x4[t], xb = x4[t + 256];
    float4 ha = h4[t], hb = h4[t + 256];
    acc[g]     = dot4(ntload4(wi + 4 * t), xa) +
                 dot4(ntload4(wi + 4 * (t + 256)), xb);
    acc[3 + g] = dot4(ntload4(wh + 4 * t), ha) +
                 dot4(ntload4(wh + 4 * (t + 256)), hb);
  }
  __shared__ float red[6][4];
  const int lane = t & 63, wid = t >> 6;
#pragma unroll
  for (int d = 0; d < 6; d++) {
    float s_ = wave_sum(acc[d]);
    if (lane == 0) red[d][wid] = s_;
  }
  __syncthreads();
  if (t == 0) {
    float gi_r = red[0][0] + red[0][1] + red[0][2] + red[0][3] + b_ih[i];
    float gi_z = red[1][0] + red[1][1] + red[1][2] + red[1][3] + b_ih[H + i];
    float gi_n = red[2][0] + red[2][1] + red[2][2] + red[2][3] + b_ih[2 * H + i];
    float gh_r = red[3][0] + red[3][1] + red[3][2] + red[3][3] + b_hh[i];
    float gh_z = red[4][0] + red[4][1] + red[4][2] + red[4][3] + b_hh[H + i];
    float gh_n = red[5][0] + red[5][1] + red[5][2] + red[5][3] + b_hh[2 * H + i];
    float r = 1.f / (1.f + expf(-(gi_r + gh_r)));
    float z = 1.f / (1.f + expf(-(gi_z + gh_z)));
    float n = tanhf(gi_n + r * gh_n);
    float h = (1.f - z) * n + z * hprev[i];
    hout_ws[i] = h;
    hout_d[i] = h;
  }
}

// part[jt][k] = sum_{j in tile jt} coef[j] * mat[j][k].  grid=(8, 32).
__global__ __launch_bounds__(256) void colsum_part_kernel(
    const float* __restrict__ mat, const float* __restrict__ coef,
    float* __restrict__ part) {
  const int k = blockIdx.x * 256 + threadIdx.x;
  const int jt = blockIdx.y;
  const int j0 = jt * 64;
  float acc = 0.f;
#pragma unroll 4
  for (int j = j0; j < j0 + 64; j++)
    acc += coef[j] * __builtin_nontemporal_load(&mat[(size_t)j * H + k]);
  part[(size_t)jt * H + k] = acc;
}

// out[k] = sum over 32 partial tiles.
__global__ __launch_bounds__(256) void combine_kernel(
    const float* __restrict__ part, float* __restrict__ out) {
  const int k = blockIdx.x * 256 + threadIdx.x;
  float acc = 0.f;
#pragma unroll
  for (int jt = 0; jt < 32; jt++) acc += part[(size_t)jt * H + k];
  out[k] = acc;
}

// e[row] = dot(enc[row], v).  One wave per row, 4 rows per block.
__global__ __launch_bounds__(256) void energies_kernel(
    const float* __restrict__ enc, const float* __restrict__ v,
    float* __restrict__ e) {
  const int wid = threadIdx.x >> 6, lane = threadIdx.x & 63;
  const int row = blockIdx.x * 4 + wid;
  const float4* r4 = (const float4*)(enc + (size_t)row * H);
  const float4* v4 = (const float4*)v;
  float acc = 0.f;
#pragma unroll
  for (int k = 0; k < 8; k++) {
    int idx = lane + 64 * k;
    acc += dot4(r4[idx], v4[idx]);
  }
  acc = wave_sum(acc);
  if (lane == 0) e[row] = acc;
}

// Redundant per-block softmax stats over e, then partial context colsum.
__global__ __launch_bounds__(256) void softmax_ctx_part_kernel(
    const float* __restrict__ enc, const float* __restrict__ e,
    float* __restrict__ part, float* __restrict__ attn_out) {
  const int t = threadIdx.x;
  const int kb = blockIdx.x;   // 0..7
  const int jt = blockIdx.y;   // 0..31
  const int lane = t & 63, wid = t >> 6;
  __shared__ float sred[4];
  __shared__ float wtile[64];
  float ev[8];
  float m = -INFINITY;
#pragma unroll
  for (int r = 0; r < 8; r++) {
    ev[r] = e[t + 256 * r];
    m = fmaxf(m, ev[r]);
  }
  float mw = wave_max(m);
  if (lane == 0) sred[wid] = mw;
  __syncthreads();
  const float M = fmaxf(fmaxf(sred[0], sred[1]), fmaxf(sred[2], sred[3]));
  float se = 0.f;
#pragma unroll
  for (int r = 0; r < 8; r++) se += expf(ev[r] - M);
  float sw = wave_sum(se);
  __syncthreads();
  if (lane == 0) sred[wid] = sw;
  __syncthreads();
  const float inv = 1.f / (sred[0] + sred[1] + sred[2] + sred[3]);
  const int j0 = jt * 64;
  if (t < 64) wtile[t] = expf(e[j0 + t] - M) * inv;
  __syncthreads();
  if (jt == 0) {
    const int s_idx = kb * 256 + t;
    attn_out[s_idx] = expf(e[s_idx] - M) * inv;
  }
  const int k = kb * 256 + t;
  float acc = 0.f;
#pragma unroll 4
  for (int j = 0; j < 64; j++)
    acc += wtile[j] * enc[(size_t)(j0 + j) * H + k];
  part[(size_t)jt * H + k] = acc;
}

// 8 rows/block, 2 rows/wave: logits + per-block (max, sumexp) pair.
__global__ __launch_bounds__(256) void logits_kernel(
    const float* __restrict__ w_out, const float* __restrict__ b_out,
    const float* __restrict__ u, float* __restrict__ logits,
    float* __restrict__ pairs) {
  const int wid = threadIdx.x >> 6, lane = threadIdx.x & 63;
  const int base = blockIdx.x * 8 + wid * 2;
  __shared__ float lvals[8];
  float l0 = -INFINITY, l1 = -INFINITY;
  if (base < V) {
    const bool has1 = (base + 1 < V);
    const float* r0 = w_out + (size_t)base * (2 * H);
    const float* r1 = w_out + (size_t)(has1 ? base + 1 : base) * (2 * H);
    const float4* u4 = (const float4*)u;
    float acc0 = 0.f, acc1 = 0.f;
#pragma unroll
    for (int k = 0; k < 16; k++) {
      int idx = lane + 64 * k;
      float4 uv = u4[idx];
      acc0 += dot4(ntload4(r0 + 4 * idx), uv);
      acc1 += dot4(ntload4(r1 + 4 * idx), uv);
    }
    acc0 = wave_sum(acc0);
    acc1 = wave_sum(acc1);
    if (lane == 0) {
      l0 = acc0 + b_out[base];
      logits[base] = l0;
      if (has1) {
        l1 = acc1 + b_out[base + 1];
        logits[base + 1] = l1;
      }
    }
  }
  if (lane == 0) { lvals[wid * 2] = l0; lvals[wid * 2 + 1] = l1; }
  __syncthreads();
  if (threadIdx.x == 0) {
    float M = -INFINITY;
#pragma unroll
    for (int i = 0; i < 8; i++) M = fmaxf(M, lvals[i]);
    float se = 0.f;
#pragma unroll
    for (int i = 0; i < 8; i++) se += expf(lvals[i] - M);  // exp(-inf)=0
    pairs[2 * blockIdx.x] = M;
    pairs[2 * blockIdx.x + 1] = se;
  }
}

// Each block redundantly combines all pairs (L2-hot, fixed order ->
// deterministic), then subtracts the constant from its slice of out.
__global__ __launch_bounds__(256) void lse_sub_kernel(
    const float* __restrict__ pairs, int npairs, float* __restrict__ out) {
  const int t = threadIdx.x;
  const int lane = t & 63, wid = t >> 6;
  __shared__ float sm[4], ss[4];
  __shared__ float cval;
  float M = -INFINITY, Ssum = 0.f;
  for (int i = t; i < npairs; i += 256) {
    float mb = pairs[2 * i], sb = pairs[2 * i + 1];
    float Mn = fmaxf(M, mb);
    Ssum = Ssum * expf(M - Mn) + sb * expf(mb - Mn);
    M = Mn;
  }
#pragma unroll
  for (int o = 32; o > 0; o >>= 1) {
    float mo = __shfl_down(M, o, 64);
    float so = __shfl_down(Ssum, o, 64);
    float Mn = fmaxf(M, mo);
    Ssum = Ssum * expf(M - Mn) + so * expf(mo - Mn);
    M = Mn;
  }
  if (lane == 0) { sm[wid] = M; ss[wid] = Ssum; }
  __syncthreads();
  if (t == 0) {
    float Mg = -INFINITY, Sg = 0.f;
#pragma unroll
    for (int i = 0; i < 4; i++) {
      float Mn = fmaxf(Mg, sm[i]);
      Sg = Sg * expf(Mg - Mn) + ss[i] * expf(sm[i] - Mn);
      Mg = Mn;
    }
    cval = Mg + logf(Sg);
  }
  __syncthreads();
  const float c = cval;
  const int i = blockIdx.x * 256 + t;
  if (i < V) out[i] -= c;
}

extern "C" void kernel_launch(void* const* d_in, const int* in_sizes, int n_in,
                              void* d_out, int out_size, void* d_ws, size_t ws_size,
                              hipStream_t stream) {
  const int*   word  = (const int*)d_in[0];
  const float* lasth = (const float*)d_in[1];
  const float* enc   = (const float*)d_in[2];
  const float* emb   = (const float*)d_in[3];
  const float* w_ih0 = (const float*)d_in[4];
  const float* w_hh0 = (const float*)d_in[5];
  const float* b_ih0 = (const float*)d_in[6];
  const float* b_hh0 = (const float*)d_in[7];
  const float* w_ih1 = (const float*)d_in[8];
  const float* w_hh1 = (const float*)d_in[9];
  const float* b_ih1 = (const float*)d_in[10];
  const float* b_hh1 = (const float*)d_in[11];
  const float* wa    = (const float*)d_in[12];
  // d_in[13] = ba: constant across s -> cancels in softmax.
  const float* w_out = (const float*)d_in[14];
  const float* b_out = (const float*)d_in[15];

  float* out      = (float*)d_out;
  float* h0_out   = out + V;
  float* h1_out   = out + V + H;
  float* attn_out = out + V + 2 * H;

  float* wsf   = (float*)d_ws;
  float* part  = wsf;                // 32*H
  float* v     = wsf + 65536;        // H
  float* e     = wsf + 67584;        // S
  float* u     = wsf + 69632;        // 2H
  float* h0    = wsf + 73728;        // H
  float* pairs = wsf + 75776;        // 2*6283

  const int nblk = (V + 7) / 8;      // 6283

  gru_kernel<<<H, 256, 0, stream>>>(w_ih0, w_hh0, b_ih0, b_hh0, emb, word,
                                    lasth, h0, h0_out);
  gru_kernel<<<H, 256, 0, stream>>>(w_ih1, w_hh1, b_ih1, b_hh1, h0, nullptr,
                                    lasth + H, u, h1_out);
  colsum_part_kernel<<<dim3(8, 32), 256, 0, stream>>>(wa, u, part);
  combine_kernel<<<8, 256, 0, stream>>>(part, v);
  energies_kernel<<<S / 4, 256, 0, stream>>>(enc, v, e);
  softmax_ctx_part_kernel<<<dim3(8, 32), 256, 0, stream>>>(enc, e, part,
                                                           attn_out);
  combine_kernel<<<8, 256, 0, stream>>>(part, u + H);
  logits_kernel<<<nblk, 256, 0, stream>>>(w_out, b_out, u, out, pairs);
  lse_sub_kernel<<<(V + 255) / 256, 256, 0, stream>>>(pairs, nblk, out);
}

// Round 7
// 197.394 us; speedup vs baseline: 4.7201x; 1.0152x over previous
//
#include <hip/hip_runtime.h>
#include <math.h>

#define H 2048
#define V 50257
#define S 2048

typedef float f32x4 __attribute__((ext_vector_type(4)));

__device__ inline float4 ntload4(const float* p) {
  f32x4 v = __builtin_nontemporal_load((const f32x4*)p);
  float4 r; r.x = v.x; r.y = v.y; r.z = v.z; r.w = v.w;
  return r;
}

__device__ inline float dot4(float4 a, float4 b) {
  return a.x * b.x + a.y * b.y + a.z * b.z + a.w * b.w;
}

__device__ inline float wave_sum(float v) {
#pragma unroll
  for (int o = 32; o > 0; o >>= 1) v += __shfl_down(v, o, 64);
  return v;
}

__device__ inline float wave_max(float v) {
#pragma unroll
  for (int o = 32; o > 0; o >>= 1) v = fmaxf(v, __shfl_down(v, o, 64));
  return v;
}

// One block per output unit i. Optionally zeroes zbuf (for the NEXT kernel's
// atomic accumulation) -- free, runs in parallel with the dot products.
__global__ __launch_bounds__(256) void gru_kernel(
    const float* __restrict__ w_ih, const float* __restrict__ w_hh,
    const float* __restrict__ b_ih, const float* __restrict__ b_hh,
    const float* __restrict__ x_base, const int* __restrict__ word,
    const float* __restrict__ hprev,
    float* __restrict__ hout_ws, float* __restrict__ hout_d,
    float* __restrict__ zbuf, int zn) {
  const float* x = word ? (x_base + (size_t)word[0] * H) : x_base;
  const int i = blockIdx.x;
  const int t = threadIdx.x;
  const int zi = i * 256 + t;
  if (zbuf && zi < zn) zbuf[zi] = 0.f;
  const float4* x4 = (const float4*)x;
  const float4* h4 = (const float4*)hprev;
  float acc[6];
#pragma unroll
  for (int d = 0; d < 6; d++) acc[d] = 0.f;
#pragma unroll
  for (int g = 0; g < 3; g++) {
    const float* wi = w_ih + (size_t)(g * H + i) * H;
    const float* wh = w_hh + (size_t)(g * H + i) * H;
    float4 xa = x4[t], xb = x4[t + 256];
    float4 ha = h4[t], hb = h4[t + 256];
    acc[g]     = dot4(ntload4(wi + 4 * t), xa) +
                 dot4(ntload4(wi + 4 * (t + 256)), xb);
    acc[3 + g] = dot4(ntload4(wh + 4 * t), ha) +
                 dot4(ntload4(wh + 4 * (t + 256)), hb);
  }
  __shared__ float red[6][4];
  const int lane = t & 63, wid = t >> 6;
#pragma unroll
  for (int d = 0; d < 6; d++) {
    float s_ = wave_sum(acc[d]);
    if (lane == 0) red[d][wid] = s_;
  }
  __syncthreads();
  if (t == 0) {
    float gi_r = red[0][0] + red[0][1] + red[0][2] + red[0][3] + b_ih[i];
    float gi_z = red[1][0] + red[1][1] + red[1][2] + red[1][3] + b_ih[H + i];
    float gi_n = red[2][0] + red[2][1] + red[2][2] + red[2][3] + b_ih[2 * H + i];
    float gh_r = red[3][0] + red[3][1] + red[3][2] + red[3][3] + b_hh[i];
    float gh_z = red[4][0] + red[4][1] + red[4][2] + red[4][3] + b_hh[H + i];
    float gh_n = red[5][0] + red[5][1] + red[5][2] + red[5][3] + b_hh[2 * H + i];
    float r = 1.f / (1.f + expf(-(gi_r + gh_r)));
    float z = 1.f / (1.f + expf(-(gi_z + gh_z)));
    float n = tanhf(gi_n + r * gh_n);
    float h = (1.f - z) * n + z * hprev[i];
    hout_ws[i] = h;
    hout_d[i] = h;
  }
}

// dst[k] += sum_{j in tile jt} coef[j]*mat[j][k], via native f32 atomics.
// dst zeroed by the preceding kernel.  grid=(8, 32).
__global__ __launch_bounds__(256) void colsum_atomic_kernel(
    const float* __restrict__ mat, const float* __restrict__ coef,
    float* __restrict__ dst) {
  const int k = blockIdx.x * 256 + threadIdx.x;
  const int j0 = blockIdx.y * 64;
  float acc = 0.f;
#pragma unroll 4
  for (int j = j0; j < j0 + 64; j++)
    acc += coef[j] * __builtin_nontemporal_load(&mat[(size_t)j * H + k]);
  unsafeAtomicAdd(&dst[k], acc);
}

// e[row] = dot(enc[row], v). One wave per row, 4 rows/block. Blocks 0..7
// also zero ctx for the next kernel's atomics.
__global__ __launch_bounds__(256) void energies_kernel(
    const float* __restrict__ enc, const float* __restrict__ v,
    float* __restrict__ e, float* __restrict__ ctx) {
  const int wid = threadIdx.x >> 6, lane = threadIdx.x & 63;
  if (blockIdx.x < 8) ctx[blockIdx.x * 256 + threadIdx.x] = 0.f;
  const int row = blockIdx.x * 4 + wid;
  const float4* r4 = (const float4*)(enc + (size_t)row * H);
  const float4* v4 = (const float4*)v;
  float acc = 0.f;
#pragma unroll
  for (int k = 0; k < 8; k++) {
    int idx = lane + 64 * k;
    acc += dot4(r4[idx], v4[idx]);
  }
  acc = wave_sum(acc);
  if (lane == 0) e[row] = acc;
}

// Redundant per-block softmax stats, then atomic partial context colsum.
__global__ __launch_bounds__(256) void softmax_ctx_kernel(
    const float* __restrict__ enc, const float* __restrict__ e,
    float* __restrict__ ctx, float* __restrict__ attn_out) {
  const int t = threadIdx.x;
  const int kb = blockIdx.x;   // 0..7
  const int jt = blockIdx.y;   // 0..31
  const int lane = t & 63, wid = t >> 6;
  __shared__ float sred[4];
  __shared__ float wtile[64];
  float ev[8];
  float m = -INFINITY;
#pragma unroll
  for (int r = 0; r < 8; r++) {
    ev[r] = e[t + 256 * r];
    m = fmaxf(m, ev[r]);
  }
  float mw = wave_max(m);
  if (lane == 0) sred[wid] = mw;
  __syncthreads();
  const float M = fmaxf(fmaxf(sred[0], sred[1]), fmaxf(sred[2], sred[3]));
  float se = 0.f;
#pragma unroll
  for (int r = 0; r < 8; r++) se += expf(ev[r] - M);
  float sw = wave_sum(se);
  __syncthreads();
  if (lane == 0) sred[wid] = sw;
  __syncthreads();
  const float inv = 1.f / (sred[0] + sred[1] + sred[2] + sred[3]);
  const int j0 = jt * 64;
  if (t < 64) wtile[t] = expf(e[j0 + t] - M) * inv;
  __syncthreads();
  if (jt == 0) {
    const int s_idx = kb * 256 + t;
    attn_out[s_idx] = expf(e[s_idx] - M) * inv;
  }
  const int k = kb * 256 + t;
  float acc = 0.f;
#pragma unroll 4
  for (int j = 0; j < 64; j++)
    acc += wtile[j] * enc[(size_t)(j0 + j) * H + k];
  unsafeAtomicAdd(&ctx[k], acc);
}

// 8 rows/block, 2 rows/wave: logits + per-block (max, sumexp) pair.
__global__ __launch_bounds__(256) void logits_kernel(
    const float* __restrict__ w_out, const float* __restrict__ b_out,
    const float* __restrict__ u, float* __restrict__ logits,
    float* __restrict__ pairs) {
  const int wid = threadIdx.x >> 6, lane = threadIdx.x & 63;
  const int base = blockIdx.x * 8 + wid * 2;
  __shared__ float lvals[8];
  float l0 = -INFINITY, l1 = -INFINITY;
  if (base < V) {
    const bool has1 = (base + 1 < V);
    const float* r0 = w_out + (size_t)base * (2 * H);
    const float* r1 = w_out + (size_t)(has1 ? base + 1 : base) * (2 * H);
    const float4* u4 = (const float4*)u;
    float acc0 = 0.f, acc1 = 0.f;
#pragma unroll
    for (int k = 0; k < 16; k++) {
      int idx = lane + 64 * k;
      float4 uv = u4[idx];
      acc0 += dot4(ntload4(r0 + 4 * idx), uv);
      acc1 += dot4(ntload4(r1 + 4 * idx), uv);
    }
    acc0 = wave_sum(acc0);
    acc1 = wave_sum(acc1);
    if (lane == 0) {
      l0 = acc0 + b_out[base];
      logits[base] = l0;
      if (has1) {
        l1 = acc1 + b_out[base + 1];
        logits[base + 1] = l1;
      }
    }
  }
  if (lane == 0) { lvals[wid * 2] = l0; lvals[wid * 2 + 1] = l1; }
  __syncthreads();
  if (threadIdx.x == 0) {
    float M = -INFINITY;
#pragma unroll
    for (int i = 0; i < 8; i++) M = fmaxf(M, lvals[i]);
    float se = 0.f;
#pragma unroll
    for (int i = 0; i < 8; i++) se += expf(lvals[i] - M);  // exp(-inf)=0
    pairs[2 * blockIdx.x] = M;
    pairs[2 * blockIdx.x + 1] = se;
  }
}

// Each block redundantly combines all pairs (L2-hot, fixed order ->
// deterministic), then subtracts the constant from its slice of out.
__global__ __launch_bounds__(256) void lse_sub_kernel(
    const float* __restrict__ pairs, int npairs, float* __restrict__ out) {
  const int t = threadIdx.x;
  const int lane = t & 63, wid = t >> 6;
  __shared__ float sm[4], ss[4];
  __shared__ float cval;
  float M = -INFINITY, Ssum = 0.f;
  for (int i = t; i < npairs; i += 256) {
    float mb = pairs[2 * i], sb = pairs[2 * i + 1];
    float Mn = fmaxf(M, mb);
    Ssum = Ssum * expf(M - Mn) + sb * expf(mb - Mn);
    M = Mn;
  }
#pragma unroll
  for (int o = 32; o > 0; o >>= 1) {
    float mo = __shfl_down(M, o, 64);
    float so = __shfl_down(Ssum, o, 64);
    float Mn = fmaxf(M, mo);
    Ssum = Ssum * expf(M - Mn) + so * expf(mo - Mn);
    M = Mn;
  }
  if (lane == 0) { sm[wid] = M; ss[wid] = Ssum; }
  __syncthreads();
  if (t == 0) {
    float Mg = -INFINITY, Sg = 0.f;
#pragma unroll
    for (int i = 0; i < 4; i++) {
      float Mn = fmaxf(Mg, sm[i]);
      Sg = Sg * expf(Mg - Mn) + ss[i] * expf(sm[i] - Mn);
      Mg = Mn;
    }
    cval = Mg + logf(Sg);
  }
  __syncthreads();
  const float c = cval;
  const int i = blockIdx.x * 256 + t;
  if (i < V) out[i] -= c;
}

extern "C" void kernel_launch(void* const* d_in, const int* in_sizes, int n_in,
                              void* d_out, int out_size, void* d_ws, size_t ws_size,
                              hipStream_t stream) {
  const int*   word  = (const int*)d_in[0];
  const float* lasth = (const float*)d_in[1];
  const float* enc   = (const float*)d_in[2];
  const float* emb   = (const float*)d_in[3];
  const float* w_ih0 = (const float*)d_in[4];
  const float* w_hh0 = (const float*)d_in[5];
  const float* b_ih0 = (const float*)d_in[6];
  const float* b_hh0 = (const float*)d_in[7];
  const float* w_ih1 = (const float*)d_in[8];
  const float* w_hh1 = (const float*)d_in[9];
  const float* b_ih1 = (const float*)d_in[10];
  const float* b_hh1 = (const float*)d_in[11];
  const float* wa    = (const float*)d_in[12];
  // d_in[13] = ba: constant across s -> cancels in softmax.
  const float* w_out = (const float*)d_in[14];
  const float* b_out = (const float*)d_in[15];

  float* out      = (float*)d_out;
  float* h0_out   = out + V;
  float* h1_out   = out + V + H;
  float* attn_out = out + V + 2 * H;

  float* wsf   = (float*)d_ws;
  float* v     = wsf;                // H      (atomic acc, zeroed by gru1)
  float* e     = wsf + 2048;         // S
  float* u     = wsf + 4096;         // 2H: [h1 | context(atomic acc)]
  float* h0    = wsf + 8192;         // H
  float* pairs = wsf + 10240;        // 2*6283

  const int nblk = (V + 7) / 8;      // 6283

  gru_kernel<<<H, 256, 0, stream>>>(w_ih0, w_hh0, b_ih0, b_hh0, emb, word,
                                    lasth, h0, h0_out, nullptr, 0);
  gru_kernel<<<H, 256, 0, stream>>>(w_ih1, w_hh1, b_ih1, b_hh1, h0, nullptr,
                                    lasth + H, u, h1_out, v, H);
  colsum_atomic_kernel<<<dim3(8, 32), 256, 0, stream>>>(wa, u, v);
  energies_kernel<<<S / 4, 256, 0, stream>>>(enc, v, e, u + H);
  softmax_ctx_kernel<<<dim3(8, 32), 256, 0, stream>>>(enc, e, u + H, attn_out);
  logits_kernel<<<nblk, 256, 0, stream>>>(w_out, b_out, u, out, pairs);
  lse_sub_kernel<<<(V + 255) / 256, 256, 0, stream>>>(pairs, nblk, out);
}